// Round 1
// baseline (3383.011 us; speedup 1.0000x reference)
//
#include <hip/hip_runtime.h>
#include <hip/hip_bf16.h>

#define Bsz 2
#define Tsz 1024
#define Vsz 50257
#define Csz 768
#define Lsz 12
#define Hsz 12
#define Msz 2048  // B*T

typedef __attribute__((ext_vector_type(8))) short short8;
typedef __attribute__((ext_vector_type(4))) float f32x4;

__device__ __forceinline__ ushort f2bf(float f) {
  union { float f; unsigned u; } v; v.f = f;
  return (ushort)((v.u + 0x7FFFu + ((v.u >> 16) & 1u)) >> 16);
}

// ---------------- embedding ----------------
__global__ void k_embed(const int* __restrict__ idx, const float* __restrict__ wte,
                        const float* __restrict__ wpe, float* __restrict__ x) {
  int m = blockIdx.x;
  int t = m & (Tsz - 1);
  const float* src = wte + (size_t)idx[m] * Csz;
  const float* pe  = wpe + (size_t)t * Csz;
  float* dst = x + (size_t)m * Csz;
  for (int c = threadIdx.x; c < Csz; c += 256)
    dst[c] = src[c] + pe[c];
}

// ---------------- layernorm (f32 in -> bf16 out) ----------------
__global__ void k_ln(const float* __restrict__ x, const float* __restrict__ w,
                     const float* __restrict__ b, ushort* __restrict__ out) {
  int m = blockIdx.x;
  const float* row = x + (size_t)m * Csz;
  int tid = threadIdx.x;
  float v0 = row[tid], v1 = row[tid + 256], v2 = row[tid + 512];
  float s = v0 + v1 + v2;
  float q = v0 * v0 + v1 * v1 + v2 * v2;
  for (int o = 32; o; o >>= 1) {
    s += __shfl_down(s, o, 64);
    q += __shfl_down(q, o, 64);
  }
  __shared__ float red[8];
  __shared__ float mv[2];
  int wid = tid >> 6, lane = tid & 63;
  if (!lane) { red[wid] = s; red[4 + wid] = q; }
  __syncthreads();
  if (!tid) {
    float S = red[0] + red[1] + red[2] + red[3];
    float Q = red[4] + red[5] + red[6] + red[7];
    float mean = S * (1.0f / Csz);
    float var = Q * (1.0f / Csz) - mean * mean;
    mv[0] = mean; mv[1] = rsqrtf(var + 1e-5f);
  }
  __syncthreads();
  float mean = mv[0], rs = mv[1];
  ushort* o = out + (size_t)m * Csz;
  o[tid]       = f2bf((v0 - mean) * rs * w[tid]       + b[tid]);
  o[tid + 256] = f2bf((v1 - mean) * rs * w[tid + 256] + b[tid + 256]);
  o[tid + 512] = f2bf((v2 - mean) * rs * w[tid + 512] + b[tid + 512]);
}

// ---------------- transpose f32 [R][Cn] -> bf16 [Cn][R] ----------------
__global__ void k_transpose_bf16(const float* __restrict__ src, ushort* __restrict__ dst,
                                 int R, int Cn) {
  __shared__ float t[32][33];
  int c0 = blockIdx.x * 32, r0 = blockIdx.y * 32;
  int tx = threadIdx.x & 31, ty = threadIdx.x >> 5;  // 32 x 8
#pragma unroll
  for (int k = 0; k < 4; k++)
    t[ty + 8 * k][tx] = src[(size_t)(r0 + ty + 8 * k) * Cn + c0 + tx];
  __syncthreads();
#pragma unroll
  for (int k = 0; k < 4; k++)
    dst[(size_t)(c0 + ty + 8 * k) * R + r0 + tx] = f2bf(t[tx][ty + 8 * k]);
}

// ---------------- f32 -> bf16 elementwise ----------------
__global__ void k_f32_to_bf16(const float* __restrict__ src, ushort* __restrict__ dst, int n) {
  int stride = gridDim.x * 256 * 4;
  for (int i = (blockIdx.x * 256 + threadIdx.x) * 4; i < n; i += stride) {
    float4 v = *(const float4*)(src + i);
    ushort4 o;
    o.x = f2bf(v.x); o.y = f2bf(v.y); o.z = f2bf(v.z); o.w = f2bf(v.w);
    *(ushort4*)(dst + i) = o;
  }
}

// ---------------- GELU (tanh approx), f32 in -> bf16 out ----------------
__global__ void k_gelu(const float* __restrict__ src, ushort* __restrict__ dst, int n) {
  int i = (blockIdx.x * 256 + threadIdx.x) * 4;
  if (i >= n) return;
  float4 v = *(const float4*)(src + i);
  float xs[4] = {v.x, v.y, v.z, v.w};
  ushort os[4];
#pragma unroll
  for (int j = 0; j < 4; j++) {
    float xv = xs[j];
    float g = 0.5f * xv * (1.0f + tanhf(0.7978845608f * (xv + 0.044715f * xv * xv * xv)));
    os[j] = f2bf(g);
  }
  ushort4 o; o.x = os[0]; o.y = os[1]; o.z = os[2]; o.w = os[3];
  *(ushort4*)(dst + i) = o;
}

// ---------------- GEMM: out[M][N] = A[M][K]bf16 @ Bt[N][K] (+bias, +res) ----------------
// 64x64 tile, 4 waves (2x2), each wave 32x32 via 2x2 mfma_f32_16x16x32_bf16 frags.
template <bool B_IS_F32>
__global__ void k_gemm_bt(const ushort* __restrict__ A, const void* __restrict__ Btv,
                          const float* __restrict__ bias, const float* res,
                          float* out, int Mdim, int N, int K) {
  __shared__ __align__(16) ushort As[64 * 40];
  __shared__ __align__(16) ushort Bs[64 * 40];
  int n0 = blockIdx.x * 64, m0 = blockIdx.y * 64;
  int tid = threadIdx.x;
  int wid = tid >> 6, lane = tid & 63, lg = lane >> 4, lr = lane & 15;
  int wm = (wid >> 1) * 32, wn = (wid & 1) * 32;
  const f32x4 FZ = {0.f, 0.f, 0.f, 0.f};
  f32x4 acc[2][2];
  acc[0][0] = FZ; acc[0][1] = FZ; acc[1][0] = FZ; acc[1][1] = FZ;

  int ldr = tid >> 2, ldc = (tid & 3) * 8;  // 64 rows x 4 chunks of 8
  for (int k0 = 0; k0 < K; k0 += 32) {
    // stage A tile
    *(int4*)&As[ldr * 40 + ldc] = *(const int4*)(A + (size_t)(m0 + ldr) * K + k0 + ldc);
    // stage B^T tile
    int n = n0 + ldr;
    if (B_IS_F32) {
      uint4 pk = {0u, 0u, 0u, 0u};
      if (n < N) {
        const float* bp = (const float*)Btv + (size_t)n * K + k0 + ldc;
        float4 x0 = *(const float4*)bp;
        float4 x1 = *(const float4*)(bp + 4);
        pk.x = (uint)f2bf(x0.x) | ((uint)f2bf(x0.y) << 16);
        pk.y = (uint)f2bf(x0.z) | ((uint)f2bf(x0.w) << 16);
        pk.z = (uint)f2bf(x1.x) | ((uint)f2bf(x1.y) << 16);
        pk.w = (uint)f2bf(x1.z) | ((uint)f2bf(x1.w) << 16);
      }
      *(uint4*)&Bs[ldr * 40 + ldc] = pk;
    } else {
      if (n < N) {
        *(int4*)&Bs[ldr * 40 + ldc] = *(const int4*)((const ushort*)Btv + (size_t)n * K + k0 + ldc);
      } else {
        int4 z = {0, 0, 0, 0};
        *(int4*)&Bs[ldr * 40 + ldc] = z;
      }
    }
    __syncthreads();
    short8 a0 = *(const short8*)&As[(wm + lr) * 40 + lg * 8];
    short8 a1 = *(const short8*)&As[(wm + 16 + lr) * 40 + lg * 8];
    short8 b0 = *(const short8*)&Bs[(wn + lr) * 40 + lg * 8];
    short8 b1 = *(const short8*)&Bs[(wn + 16 + lr) * 40 + lg * 8];
    acc[0][0] = __builtin_amdgcn_mfma_f32_16x16x32_bf16(a0, b0, acc[0][0], 0, 0, 0);
    acc[0][1] = __builtin_amdgcn_mfma_f32_16x16x32_bf16(a0, b1, acc[0][1], 0, 0, 0);
    acc[1][0] = __builtin_amdgcn_mfma_f32_16x16x32_bf16(a1, b0, acc[1][0], 0, 0, 0);
    acc[1][1] = __builtin_amdgcn_mfma_f32_16x16x32_bf16(a1, b1, acc[1][1], 0, 0, 0);
    __syncthreads();
  }
#pragma unroll
  for (int mi = 0; mi < 2; mi++)
#pragma unroll
    for (int ni = 0; ni < 2; ni++) {
      int gn = n0 + wn + ni * 16 + lr;
      if (gn < N) {
        float bv = bias ? bias[gn] : 0.f;
#pragma unroll
        for (int i = 0; i < 4; i++) {
          int gm = m0 + wm + mi * 16 + 4 * lg + i;
          size_t o = (size_t)gm * N + gn;
          float v = acc[mi][ni][i] + bv;
          if (res) v += res[o];
          out[o] = v;
        }
      }
    }
}

// ---------------- flash attention (causal), qkv f32 -> y bf16 ----------------
// grid (T/64, B*H); block 256 = 4 waves; wave handles 16 q rows.
__global__ void k_attn(const float* __restrict__ qkv, ushort* __restrict__ ybf) {
  __shared__ __align__(16) ushort Ks[32 * 72];
  __shared__ __align__(16) ushort Vs[64 * 40];   // transposed: [d][k]
  __shared__ __align__(16) ushort Ps[4 * 16 * 40];
  int q0 = blockIdx.x * 64;
  int bh = blockIdx.y;
  int b = bh / Hsz, h = bh % Hsz;
  int tid = threadIdx.x, wid = tid >> 6, lane = tid & 63, lg = lane >> 4, lr = lane & 15;
  const float* base = qkv + (size_t)b * Tsz * 2304;

  // Q fragments (A operand): row = lr, k(d) = c*32 + lg*8 + i
  short8 aq[2];
  {
    int qt = q0 + wid * 16 + lr;
    const float* qp = base + (size_t)qt * 2304 + h * 64;
#pragma unroll
    for (int c = 0; c < 2; c++) {
      float4 x0 = *(const float4*)(qp + c * 32 + lg * 8);
      float4 x1 = *(const float4*)(qp + c * 32 + lg * 8 + 4);
      short8 v;
      v[0] = (short)f2bf(x0.x); v[1] = (short)f2bf(x0.y);
      v[2] = (short)f2bf(x0.z); v[3] = (short)f2bf(x0.w);
      v[4] = (short)f2bf(x1.x); v[5] = (short)f2bf(x1.y);
      v[6] = (short)f2bf(x1.z); v[7] = (short)f2bf(x1.w);
      aq[c] = v;
    }
  }

  const f32x4 FZ = {0.f, 0.f, 0.f, 0.f};
  f32x4 of[4];
  of[0] = FZ; of[1] = FZ; of[2] = FZ; of[3] = FZ;
  float mrow[4] = {-INFINITY, -INFINITY, -INFINITY, -INFINITY};
  float lrow[4] = {0.f, 0.f, 0.f, 0.f};

  int nkt = q0 / 32 + 2;
  for (int kt = 0; kt < nkt; kt++) {
    int k0 = kt * 32;
    // stage K (bf16, row-major padded) and V (bf16, transposed padded)
    {
      int row = tid >> 3, dblk = (tid & 7) * 8;
      const float* kp = base + (size_t)(k0 + row) * 2304 + 768 + h * 64 + dblk;
      float4 x0 = *(const float4*)kp;
      float4 x1 = *(const float4*)(kp + 4);
      uint4 pk;
      pk.x = (uint)f2bf(x0.x) | ((uint)f2bf(x0.y) << 16);
      pk.y = (uint)f2bf(x0.z) | ((uint)f2bf(x0.w) << 16);
      pk.z = (uint)f2bf(x1.x) | ((uint)f2bf(x1.y) << 16);
      pk.w = (uint)f2bf(x1.z) | ((uint)f2bf(x1.w) << 16);
      *(uint4*)&Ks[row * 72 + dblk] = pk;
      const float* vp = base + (size_t)(k0 + row) * 2304 + 1536 + h * 64 + dblk;
      float4 v0 = *(const float4*)vp;
      float4 v1 = *(const float4*)(vp + 4);
      float vv[8] = {v0.x, v0.y, v0.z, v0.w, v1.x, v1.y, v1.z, v1.w};
#pragma unroll
      for (int j = 0; j < 8; j++) Vs[(dblk + j) * 40 + row] = f2bf(vv[j]);
    }
    __syncthreads();

    // S = Q K^T  (16 rows x 32 keys per wave)
    f32x4 sf[2];
    sf[0] = FZ; sf[1] = FZ;
#pragma unroll
    for (int c = 0; c < 2; c++) {
#pragma unroll
      for (int nf = 0; nf < 2; nf++) {
        short8 bk = *(const short8*)&Ks[(nf * 16 + lr) * 72 + c * 32 + lg * 8];
        sf[nf] = __builtin_amdgcn_mfma_f32_16x16x32_bf16(aq[c], bk, sf[nf], 0, 0, 0);
      }
    }

    // online softmax per row (row = 4*lg + i, cols distributed over 16 lanes)
    float p[2][4];
#pragma unroll
    for (int i = 0; i < 4; i++) {
      int qr = q0 + wid * 16 + 4 * lg + i;
      float s0 = sf[0][i] * 0.125f;
      float s1 = sf[1][i] * 0.125f;
      if (k0 + lr > qr) s0 = -INFINITY;
      if (k0 + 16 + lr > qr) s1 = -INFINITY;
      float rm = fmaxf(s0, s1);
#pragma unroll
      for (int o = 1; o < 16; o <<= 1) rm = fmaxf(rm, __shfl_xor(rm, o, 16));
      float mnew = fmaxf(mrow[i], rm);
      float scale = __expf(mrow[i] - mnew);
      float p0 = __expf(s0 - mnew);
      float p1 = __expf(s1 - mnew);
      float rs = p0 + p1;
#pragma unroll
      for (int o = 1; o < 16; o <<= 1) rs += __shfl_xor(rs, o, 16);
      lrow[i] = lrow[i] * scale + rs;
      mrow[i] = mnew;
      p[0][i] = p0; p[1][i] = p1;
      of[0][i] *= scale; of[1][i] *= scale; of[2][i] *= scale; of[3][i] *= scale;
    }

    // P -> LDS (re-layout D-frag -> A-frag)
#pragma unroll
    for (int nf = 0; nf < 2; nf++)
#pragma unroll
      for (int i = 0; i < 4; i++)
        Ps[(wid * 16 + 4 * lg + i) * 40 + nf * 16 + lr] = f2bf(p[nf][i]);
    __syncthreads();

    // O += P V
    short8 ap = *(const short8*)&Ps[(wid * 16 + lr) * 40 + lg * 8];
#pragma unroll
    for (int df = 0; df < 4; df++) {
      short8 bv = *(const short8*)&Vs[(df * 16 + lr) * 40 + lg * 8];
      of[df] = __builtin_amdgcn_mfma_f32_16x16x32_bf16(ap, bv, of[df], 0, 0, 0);
    }
    __syncthreads();
  }

  // normalize and write y (bf16) at [b*T+q][h*64+d]
  ushort* yp = ybf + (size_t)b * Tsz * Csz;
#pragma unroll
  for (int df = 0; df < 4; df++)
#pragma unroll
    for (int i = 0; i < 4; i++) {
      int qr = q0 + wid * 16 + 4 * lg + i;
      float v = of[df][i] / lrow[i];
      yp[(size_t)qr * Csz + h * 64 + df * 16 + lr] = f2bf(v);
    }
}

// ---------------- host ----------------
extern "C" void kernel_launch(void* const* d_in, const int* in_sizes, int n_in,
                              void* d_out, int out_size, void* d_ws, size_t ws_size,
                              hipStream_t stream) {
  (void)in_sizes; (void)n_in; (void)out_size;
  const int* idx      = (const int*)d_in[0];
  const float* wte    = (const float*)d_in[1];
  const float* wpe    = (const float*)d_in[2];
  const float* ln1_w  = (const float*)d_in[3];
  const float* ln1_b  = (const float*)d_in[4];
  const float* attn_w = (const float*)d_in[5];
  const float* attn_b = (const float*)d_in[6];
  const float* proj_w = (const float*)d_in[7];
  const float* proj_b = (const float*)d_in[8];
  const float* ln2_w  = (const float*)d_in[9];
  const float* ln2_b  = (const float*)d_in[10];
  const float* fc_w   = (const float*)d_in[11];
  const float* fc_b   = (const float*)d_in[12];
  const float* fc2_w  = (const float*)d_in[13];
  const float* fc2_b  = (const float*)d_in[14];
  const float* lnf_w  = (const float*)d_in[15];
  const float* lnf_b  = (const float*)d_in[16];
  const float* lm_w   = (const float*)d_in[17];
  float* out = (float*)d_out;

  char* ws = (char*)d_ws;
  float*  x    = (float*)(ws + 0);            // 2048*768*4   = 6291456
  float*  qkv  = (float*)(ws + 6291456);      // 2048*2304*4  = 18874368
  float*  fca  = (float*)(ws + 25165824);     // 2048*3072*4  = 25165824
  ushort* abuf = (ushort*)(ws + 50331648);    // 2048*3072*2  = 12582912
  ushort* wT   = (ushort*)(ws + 62914560);    // 3072*768*2   = 4718592
  ushort* lmw  = (ushort*)(ws + 67633152);    // 50257*768*2  = 77194752
  const size_t NEED_FULL = 144827904ull;
  bool lm_bf16 = ws_size >= NEED_FULL;

  k_embed<<<Msz, 256, 0, stream>>>(idx, wte, wpe, x);
  if (lm_bf16)
    k_f32_to_bf16<<<4096, 256, 0, stream>>>(lm_w, lmw, Vsz * Csz);

  for (int l = 0; l < Lsz; l++) {
    // --- attention ---
    k_ln<<<Msz, 256, 0, stream>>>(x, ln1_w + l * Csz, ln1_b + l * Csz, abuf);
    k_transpose_bf16<<<dim3(3 * Csz / 32, Csz / 32), 256, 0, stream>>>(
        attn_w + (size_t)l * Csz * 3 * Csz, wT, Csz, 3 * Csz);
    k_gemm_bt<false><<<dim3(3 * Csz / 64, Msz / 64), 256, 0, stream>>>(
        abuf, wT, attn_b + (size_t)l * 3 * Csz, nullptr, qkv, Msz, 3 * Csz, Csz);
    k_attn<<<dim3(Tsz / 64, Bsz * Hsz), 256, 0, stream>>>(qkv, abuf);
    k_transpose_bf16<<<dim3(Csz / 32, Csz / 32), 256, 0, stream>>>(
        proj_w + (size_t)l * Csz * Csz, wT, Csz, Csz);
    k_gemm_bt<false><<<dim3(Csz / 64, Msz / 64), 256, 0, stream>>>(
        abuf, wT, proj_b + (size_t)l * Csz, x, x, Msz, Csz, Csz);
    // --- mlp ---
    k_ln<<<Msz, 256, 0, stream>>>(x, ln2_w + l * Csz, ln2_b + l * Csz, abuf);
    k_transpose_bf16<<<dim3(4 * Csz / 32, Csz / 32), 256, 0, stream>>>(
        fc_w + (size_t)l * Csz * 4 * Csz, wT, Csz, 4 * Csz);
    k_gemm_bt<false><<<dim3(4 * Csz / 64, Msz / 64), 256, 0, stream>>>(
        abuf, wT, fc_b + (size_t)l * 4 * Csz, nullptr, fca, Msz, 4 * Csz, Csz);
    k_gelu<<<(Msz * 4 * Csz) / 1024, 256, 0, stream>>>(fca, abuf, Msz * 4 * Csz);
    k_transpose_bf16<<<dim3(Csz / 32, 4 * Csz / 32), 256, 0, stream>>>(
        fc2_w + (size_t)l * 4 * Csz * Csz, wT, 4 * Csz, Csz);
    k_gemm_bt<false><<<dim3(Csz / 64, Msz / 64), 256, 0, stream>>>(
        abuf, wT, fc2_b + (size_t)l * Csz, x, x, Msz, Csz, 4 * Csz);
  }

  k_ln<<<Msz, 256, 0, stream>>>(x, lnf_w, lnf_b, abuf);
  int ntiles = (Vsz + 63) / 64;  // 786
  if (lm_bf16) {
    k_gemm_bt<false><<<dim3(ntiles, Msz / 64), 256, 0, stream>>>(
        abuf, lmw, nullptr, nullptr, out, Msz, Vsz, Csz);
  } else {
    k_gemm_bt<true><<<dim3(ntiles, Msz / 64), 256, 0, stream>>>(
        abuf, lm_w, nullptr, nullptr, out, Msz, Vsz, Csz);
  }
}